// Round 1
// baseline (434.268 us; speedup 1.0000x reference)
//
#include <hip/hip_runtime.h>

// Problem constants (fixed by setup_inputs):
//   B=16, L=4096 (64x64 grid), H=1152, output_length=1024 -> k=2, k^2=4
#define BB 16
#define LL 4096
#define HH 1152
#define OUT_LEN 1024
#define KK 2
#define CAP 8              // inverse-list capacity per segment (data gives exactly 4)
#define H4 (HH / 4)        // 288 float4 per row

// ---------------- Kernel A: per-batch max_x = max(clamp(pos_x,0)) + 1 ----------------
__global__ void maxx_kernel(const int* __restrict__ pos, int* __restrict__ maxx) {
    const int b = blockIdx.x;
    const int tid = threadIdx.x;
    int m = 0;
    for (int i = tid; i < LL; i += 256) {
        int x = pos[((size_t)b * LL + i) * 2];
        if (x < 0) x = 0;
        m = max(m, x);
    }
    __shared__ int sm[256];
    sm[tid] = m;
    __syncthreads();
    for (int s = 128; s > 0; s >>= 1) {
        if (tid < s) sm[tid] = max(sm[tid], sm[tid + s]);
        __syncthreads();
    }
    if (tid == 0) maxx[b] = sm[0] + 1;
}

// ---------------- Kernel B: build inverse lists (seg -> patch indices) ----------------
__global__ void build_inv(const int* __restrict__ pos, const int* __restrict__ maxx,
                          int* __restrict__ cnt, int* __restrict__ inv) {
    const int fl = blockIdx.x * 256 + threadIdx.x;   // fl = b*LL + i
    if (fl >= BB * LL) return;
    const int b = fl >> 12;           // / LL
    const int i = fl & (LL - 1);      // % LL
    int x = pos[2 * (size_t)fl];
    int y = pos[2 * (size_t)fl + 1];
    x = max(x, 0);
    y = max(y, 0);
    const int segw = maxx[b] / KK;
    const int seg = x / KK + segw * (y / KK);
    const int base = b * OUT_LEN + seg;
    const int slot = atomicAdd(&cnt[base], 1);
    if (slot < CAP) inv[base * CAP + slot] = i;
}

// ---------------- Kernel C: gather + mean(k^2) + scale, plus mask chunk ----------------
__global__ __launch_bounds__(256) void gather_pool(
    const float* __restrict__ hs, const int* __restrict__ pad,
    const int* __restrict__ cnt, const int* __restrict__ inv,
    float* __restrict__ out) {
    const int id = blockIdx.x * 256 + threadIdx.x;   // [0, BB*OUT_LEN*H4)
    const int h4 = id % H4;
    const int t  = id / H4;                           // t = b*OUT_LEN + s
    const int b  = t >> 10;                           // / OUT_LEN

    int c = cnt[t];
    const int cc = min(c, CAP);

    const float4* __restrict__ hp = (const float4*)hs;
    float4 acc = make_float4(0.f, 0.f, 0.f, 0.f);
    #pragma unroll 4
    for (int j = 0; j < cc; ++j) {
        const int i = inv[t * CAP + j];
        if (pad[(size_t)b * LL + i] == 0) {           // padded patches contribute 0
            float4 v = hp[(size_t)(b * LL + i) * H4 + h4];
            acc.x += v.x; acc.y += v.y; acc.z += v.z; acc.w += v.w;
        }
    }
    // pooled = sum / k^2; then * sqrt(H)
    const float scale = 33.941125496954285f / (float)(KK * KK);
    acc.x *= scale; acc.y *= scale; acc.z *= scale; acc.w *= scale;
    ((float4*)out)[id] = acc;

    // mask output: counts > 0 (includes padded patches, matching segment_sum of ones)
    if (h4 == 0) out[(size_t)BB * OUT_LEN * HH + t] = (c > 0) ? 1.0f : 0.0f;
}

extern "C" void kernel_launch(void* const* d_in, const int* in_sizes, int n_in,
                              void* d_out, int out_size, void* d_ws, size_t ws_size,
                              hipStream_t stream) {
    const float* hs  = (const float*)d_in[0];   // [B, L, H] fp32
    const int*   pos = (const int*)d_in[1];     // [B, L, 2] int
    const int*   pad = (const int*)d_in[2];     // [B, L] bool->int
    float* out = (float*)d_out;                 // [B,1024,1152] fp32 ++ [B,1024] mask

    int* ws   = (int*)d_ws;
    int* maxx = ws;                             // BB ints (64-padded)
    int* cnt  = ws + 64;                        // BB*OUT_LEN ints
    int* inv  = cnt + BB * OUT_LEN;             // BB*OUT_LEN*CAP ints

    hipMemsetAsync(cnt, 0, BB * OUT_LEN * sizeof(int), stream);
    maxx_kernel<<<BB, 256, 0, stream>>>(pos, maxx);
    build_inv<<<(BB * LL) / 256, 256, 0, stream>>>(pos, maxx, cnt, inv);
    gather_pool<<<(BB * OUT_LEN * H4) / 256, 256, 0, stream>>>(hs, pad, cnt, inv, out);
}

// Round 3
// 418.477 us; speedup vs baseline: 1.0377x; 1.0377x over previous
//
#include <hip/hip_runtime.h>

// Problem constants (fixed by setup_inputs):
//   B=16, L=4096 (64x64 grid), H=1152, output_length=1024 -> k=2, k^2=4
#define BB 16
#define LL 4096
#define HH 1152
#define OUT_LEN 1024
#define KK 2
#define CAP 8              // inverse-list capacity per segment (data gives exactly 4)
#define H4 (HH / 4)        // 288 float4 per row
#define H8 (HH / 8)        // 144 float4-pairs per row

typedef float vf4 __attribute__((ext_vector_type(4)));   // native vector for nontemporal builtins

// ---------------- Kernel A: per-batch max_x = max(clamp(pos_x,0)) + 1, and zero cnt ----------------
__global__ void maxx_zero_kernel(const int* __restrict__ pos, int* __restrict__ maxx,
                                 int* __restrict__ cnt) {
    const int b = blockIdx.x;
    const int tid = threadIdx.x;
    // zero this batch's segment counters (1024 ints, 256 threads x 4)
    #pragma unroll
    for (int j = 0; j < OUT_LEN / 256; ++j) cnt[b * OUT_LEN + j * 256 + tid] = 0;

    int m = 0;
    for (int i = tid; i < LL; i += 256) {
        int x = pos[((size_t)b * LL + i) * 2];
        m = max(m, max(x, 0));
    }
    __shared__ int sm[256];
    sm[tid] = m;
    __syncthreads();
    for (int s = 128; s > 0; s >>= 1) {
        if (tid < s) sm[tid] = max(sm[tid], sm[tid + s]);
        __syncthreads();
    }
    if (tid == 0) maxx[b] = sm[0] + 1;
}

// ---------------- Kernel B: build inverse lists (seg -> patch indices, pad folded into sign bit) ----
__global__ void build_inv(const int* __restrict__ pos, const int* __restrict__ pad,
                          const int* __restrict__ maxx,
                          int* __restrict__ cnt, int* __restrict__ inv) {
    const int fl = blockIdx.x * 256 + threadIdx.x;   // fl = b*LL + i, grid sized exactly
    const int b = fl >> 12;           // / LL
    const int i = fl & (LL - 1);      // % LL
    int x = max(pos[2 * (size_t)fl], 0);
    int y = max(pos[2 * (size_t)fl + 1], 0);
    const int segw = maxx[b] / KK;
    const int seg = x / KK + segw * (y / KK);
    const int base = b * OUT_LEN + seg;
    const int slot = atomicAdd(&cnt[base], 1);
    if (slot < CAP) inv[base * CAP + slot] = pad[fl] ? (i | 0x80000000) : i;
}

// ---------------- Kernel C: gather + mean(k^2) + scale, plus mask chunk ----------------
__global__ __launch_bounds__(256) void gather_pool(
    const float* __restrict__ hs, const int* __restrict__ cnt, const int* __restrict__ inv,
    float* __restrict__ out) {
    const int id = blockIdx.x * 256 + threadIdx.x;   // [0, BB*OUT_LEN*H8)
    const int h8 = id % H8;                           // which 32B chunk of the row
    const int t  = id / H8;                           // t = b*OUT_LEN + s
    const int b  = t >> 10;                           // / OUT_LEN

    const int c  = cnt[t];
    const int cc = min(c, CAP);

    const vf4* __restrict__ hp = (const vf4*)hs;
    vf4 a0 = (vf4)0.0f;
    vf4 a1 = (vf4)0.0f;
    #pragma unroll 4
    for (int j = 0; j < cc; ++j) {
        const int ii = inv[t * CAP + j];
        if (ii >= 0) {                                // padded patches (sign bit set) contribute 0
            const vf4* p = hp + (size_t)(b * LL + ii) * H4 + h8 * 2;
            a0 += __builtin_nontemporal_load(p);
            a1 += __builtin_nontemporal_load(p + 1);
        }
    }
    // pooled = sum / k^2; then * sqrt(H):  sqrt(1152)/4
    const float scale = 8.485281374238571f;
    a0 *= scale;
    a1 *= scale;

    vf4* op = (vf4*)out + (size_t)t * H4 + h8 * 2;
    __builtin_nontemporal_store(a0, op);
    __builtin_nontemporal_store(a1, op + 1);

    // mask output: counts > 0 (includes padded patches, matching segment_sum of ones)
    if (h8 == 0) out[(size_t)BB * OUT_LEN * HH + t] = (c > 0) ? 1.0f : 0.0f;
}

extern "C" void kernel_launch(void* const* d_in, const int* in_sizes, int n_in,
                              void* d_out, int out_size, void* d_ws, size_t ws_size,
                              hipStream_t stream) {
    const float* hs  = (const float*)d_in[0];   // [B, L, H] fp32
    const int*   pos = (const int*)d_in[1];     // [B, L, 2] int
    const int*   pad = (const int*)d_in[2];     // [B, L] bool->int
    float* out = (float*)d_out;                 // [B,1024,1152] fp32 ++ [B,1024] mask

    int* ws   = (int*)d_ws;
    int* maxx = ws;                             // BB ints (64-padded)
    int* cnt  = ws + 64;                        // BB*OUT_LEN ints
    int* inv  = cnt + BB * OUT_LEN;             // BB*OUT_LEN*CAP ints

    maxx_zero_kernel<<<BB, 256, 0, stream>>>(pos, maxx, cnt);
    build_inv<<<(BB * LL) / 256, 256, 0, stream>>>(pos, pad, maxx, cnt, inv);
    gather_pool<<<(BB * OUT_LEN * H8) / 256, 256, 0, stream>>>(hs, cnt, inv, out);
}